// Round 1
// baseline (1782.741 us; speedup 1.0000x reference)
//
#include <hip/hip_runtime.h>
#include <hip/hip_bf16.h>

#define N 8192
#define EPS 1e-8f

// ---- bf16 helpers (manual, positive finite values only) ----
__device__ __forceinline__ unsigned short f2bf(float f) {
    // round-to-nearest-even
    unsigned int u = __float_as_uint(f);
    unsigned int rounding = 0x7FFFu + ((u >> 16) & 1u);
    return (unsigned short)((u + rounding) >> 16);
}
__device__ __forceinline__ float bflo(unsigned int w) { return __uint_as_float(w << 16); }
__device__ __forceinline__ float bfhi(unsigned int w) { return __uint_as_float(w & 0xffff0000u); }

// dot of 8 packed bf16 (uint4) with 8 floats (two float4)
__device__ __forceinline__ float dot8(uint4 kv, float4 xa, float4 xb) {
    float a = 0.f;
    a = fmaf(bflo(kv.x), xa.x, a);
    a = fmaf(bfhi(kv.x), xa.y, a);
    a = fmaf(bflo(kv.y), xa.z, a);
    a = fmaf(bfhi(kv.y), xa.w, a);
    a = fmaf(bflo(kv.z), xb.x, a);
    a = fmaf(bfhi(kv.z), xb.y, a);
    a = fmaf(bflo(kv.w), xb.z, a);
    a = fmaf(bfhi(kv.w), xb.w, a);
    return a;
}

// ---- init v = 1/N ----
__global__ __launch_bounds__(256) void init_v_kernel(float* __restrict__ v) {
    int i = blockIdx.x * 256 + threadIdx.x;
    if (i < N) v[i] = 1.0f / (float)N;
}

// ---- build K (bf16, row-major) and KT (bf16, transposed) from s, m ----
// 64x64 tile per block, 256 threads. LDS transpose for coalesced KT writes.
__global__ __launch_bounds__(256) void build_K_kernel(
    const float* __restrict__ s, const float* __restrict__ m,
    unsigned short* __restrict__ K, unsigned short* __restrict__ KT) {
    __shared__ unsigned short tile[64][65];
    const int bx = blockIdx.x;   // col tile
    const int by = blockIdx.y;   // row tile
    const int tid = threadIdx.x;
    const int c4 = tid & 15;     // which float4 within the 64-wide tile
    const int r0 = tid >> 4;     // 0..15

    #pragma unroll
    for (int p = 0; p < 4; ++p) {
        const int r = r0 + p * 16;          // 0..63
        const int row = by * 64 + r;
        const int col = bx * 64 + c4 * 4;
        const size_t idx = (size_t)row * N + col;
        const float4 s4 = *(const float4*)(s + idx);
        const float4 m4 = *(const float4*)(m + idx);
        const unsigned short k0 = f2bf(__expf(s4.x) * m4.x);
        const unsigned short k1 = f2bf(__expf(s4.y) * m4.y);
        const unsigned short k2 = f2bf(__expf(s4.z) * m4.z);
        const unsigned short k3 = f2bf(__expf(s4.w) * m4.w);
        ushort4 pk = make_ushort4(k0, k1, k2, k3);
        *(ushort4*)(K + idx) = pk;
        tile[r][c4 * 4 + 0] = k0;
        tile[r][c4 * 4 + 1] = k1;
        tile[r][c4 * 4 + 2] = k2;
        tile[r][c4 * 4 + 3] = k3;
    }
    __syncthreads();
    #pragma unroll
    for (int p = 0; p < 4; ++p) {
        const int c_local = (tid >> 4) + p * 16;   // 0..63 (KT row within tile)
        const int r4 = (tid & 15) * 4;             // 0..60 (KT col group)
        ushort4 pk;
        pk.x = tile[r4 + 0][c_local];
        pk.y = tile[r4 + 1][c_local];
        pk.z = tile[r4 + 2][c_local];
        pk.w = tile[r4 + 3][c_local];
        *(ushort4*)(KT + (size_t)(bx * 64 + c_local) * N + by * 64 + r4) = pk;
    }
}

// ---- fused matvec + reciprocal: out[i] = 1 / (eps + sum_j M[i][j] * x[j]) ----
// M row-major 8192x8192 bf16. 8 rows per block, 256 threads.
#define RPB 8
__global__ __launch_bounds__(256) void matvec_recip_kernel(
    const unsigned short* __restrict__ M, const float* __restrict__ x,
    float* __restrict__ out) {
    const int rowBase = blockIdx.x * RPB;
    const int tid = threadIdx.x;

    float acc[RPB];
    #pragma unroll
    for (int r = 0; r < RPB; ++r) acc[r] = 0.f;

    #pragma unroll
    for (int sweep = 0; sweep < 4; ++sweep) {
        const int col = sweep * 2048 + tid * 8;
        const float4 xa = *(const float4*)(x + col);
        const float4 xb = *(const float4*)(x + col + 4);
        #pragma unroll
        for (int r = 0; r < RPB; ++r) {
            const uint4 kv = *(const uint4*)(M + (size_t)(rowBase + r) * N + col);
            acc[r] += dot8(kv, xa, xb);
        }
    }

    // reduce across the block: wave shuffle then LDS
    __shared__ float wred[RPB][4];
    const int lane = tid & 63;
    const int wave = tid >> 6;
    #pragma unroll
    for (int r = 0; r < RPB; ++r) {
        float a = acc[r];
        #pragma unroll
        for (int off = 32; off > 0; off >>= 1) a += __shfl_down(a, off, 64);
        if (lane == 0) wred[r][wave] = a;
    }
    __syncthreads();
    if (tid < RPB) {
        const float ssum = wred[tid][0] + wred[tid][1] + wred[tid][2] + wred[tid][3];
        out[rowBase + tid] = 1.0f / (ssum + EPS);
    }
}

// ---- final: out[i][j] = u[i] * exp(s[i][j]) * m[i][j] * v[j] (fp32 exact K) ----
__global__ __launch_bounds__(256) void final_kernel(
    const float* __restrict__ s, const float* __restrict__ m,
    const float* __restrict__ u, const float* __restrict__ v,
    float* __restrict__ out) {
    const int row = blockIdx.x;
    const float ur = u[row];
    const int tid = threadIdx.x;
    #pragma unroll
    for (int sweep = 0; sweep < 8; ++sweep) {
        const int col = sweep * 1024 + tid * 4;
        const size_t idx = (size_t)row * N + col;
        const float4 s4 = *(const float4*)(s + idx);
        const float4 m4 = *(const float4*)(m + idx);
        const float4 v4 = *(const float4*)(v + col);
        float4 o;
        o.x = ur * __expf(s4.x) * m4.x * v4.x;
        o.y = ur * __expf(s4.y) * m4.y * v4.y;
        o.z = ur * __expf(s4.z) * m4.z * v4.z;
        o.w = ur * __expf(s4.w) * m4.w * v4.w;
        *(float4*)(out + idx) = o;
    }
}

extern "C" void kernel_launch(void* const* d_in, const int* in_sizes, int n_in,
                              void* d_out, int out_size, void* d_ws, size_t ws_size,
                              hipStream_t stream) {
    const float* eta = (const float*)d_in[0];
    const float* s = eta;                       // eta_result[0]: scores
    const float* m = eta + (size_t)N * N;       // eta_result[1]: mask
    float* out = (float*)d_out;

    // workspace layout: K bf16 (128 MiB) | KT bf16 (128 MiB) | u (32 KiB) | v (32 KiB)
    unsigned short* K  = (unsigned short*)d_ws;
    unsigned short* KT = K + (size_t)N * N;
    float* u = (float*)(KT + (size_t)N * N);
    float* v = u + N;

    init_v_kernel<<<N / 256, 256, 0, stream>>>(v);
    build_K_kernel<<<dim3(N / 64, N / 64), 256, 0, stream>>>(s, m, K, KT);
    for (int it = 0; it < 20; ++it) {
        matvec_recip_kernel<<<N / RPB, 256, 0, stream>>>(K, v, u);   // u = 1/(K v + eps)
        matvec_recip_kernel<<<N / RPB, 256, 0, stream>>>(KT, u, v);  // v = 1/(K^T u + eps)
    }
    final_kernel<<<N, 256, 0, stream>>>(s, m, u, v, out);
}